// Round 1
// baseline (1807.463 us; speedup 1.0000x reference)
//
#include <hip/hip_runtime.h>
#include <math.h>

#define NN 50000
#define NE 640000
#define DIM 128
#define NH 8

__device__ __forceinline__ float wave_sum64(float v) {
  #pragma unroll
  for (int m = 32; m >= 1; m >>= 1) v += __shfl_xor(v, m, 64);
  return v;
}

// ---------------------------------------------------------------------------
// Generic row-GEMM: out[n, out_off + j] = act( sum_i x[n*in_stride + i] * W[i*w_stride + w_off + j] )
// 128-wide input rows, 128 output cols per launch. Weights staged in 64KB LDS.
// One wave per row; lane handles cols l and l+64. Row base is wave-uniform
// (readfirstlane) so row loads can go through the scalar path.
// ---------------------------------------------------------------------------
__global__ __launch_bounds__(256) void gemm128(
    const float* __restrict__ xin, int in_stride,
    const float* __restrict__ Wsrc, int w_stride, int w_off,
    float* __restrict__ outp, int out_stride, int out_off,
    int do_relu, int nrows)
{
  __shared__ float Wl[DIM * DIM];          // 64 KB exactly
  for (int t = threadIdx.x; t < DIM * DIM; t += 256) {
    int i = t >> 7, j = t & 127;
    Wl[t] = Wsrc[i * w_stride + w_off + j];
  }
  __syncthreads();
  const int wid = threadIdx.x >> 6;
  const int l   = threadIdx.x & 63;
  for (int n = blockIdx.x * 4 + wid; n < nrows; n += gridDim.x * 4) {
    const int nu = __builtin_amdgcn_readfirstlane(n);
    const float* __restrict__ row = xin + (size_t)nu * in_stride;
    float acc0 = 0.f, acc1 = 0.f;
    #pragma unroll 8
    for (int i = 0; i < DIM; ++i) {
      float v = row[i];
      acc0 = fmaf(v, Wl[i * DIM + l], acc0);
      acc1 = fmaf(v, Wl[i * DIM + l + 64], acc1);
    }
    if (do_relu) { acc0 = fmaxf(acc0, 0.f); acc1 = fmaxf(acc1, 0.f); }
    float* op = outp + (size_t)n * out_stride + out_off;
    op[l] = acc0;
    op[l + 64] = acc1;
  }
}

// ---------------------------------------------------------------------------
// Edge logits: scores = dot(k[src], q[dst]) per head / 4 + basic_attn * W_dis
// Segment-max into mx via atomicMax on a monotonic uint key.
// ---------------------------------------------------------------------------
__global__ __launch_bounds__(256) void edge_logits_k(
    const float* __restrict__ kbuf, const float* __restrict__ qbuf,
    const float* __restrict__ ba, const int* __restrict__ src,
    const int* __restrict__ dst, const float* __restrict__ Wdis,
    float* __restrict__ elog, unsigned* __restrict__ mx)
{
  int idx = blockIdx.x * 256 + threadIdx.x;
  if (idx >= NE * NH) return;
  int e = idx >> 3, h = idx & 7;
  int s = src[e], t = dst[e];
  const float* kp = kbuf + (size_t)s * DIM + h * 16;
  const float* qp = qbuf + (size_t)t * DIM + h * 16;
  float sc = 0.f;
  #pragma unroll
  for (int i = 0; i < 16; ++i) sc = fmaf(kp[i], qp[i], sc);
  sc = sc * 0.25f + ba[e] * Wdis[h];
  elog[idx] = sc;
  unsigned u = __float_as_uint(sc);
  u = (u & 0x80000000u) ? ~u : (u | 0x80000000u);   // monotonic key, >0 for finite
  atomicMax(&mx[t * NH + h], u);
}

// exp(logit - mx[dst]) in place, segment-sum into den
__global__ __launch_bounds__(256) void edge_exp_k(
    const int* __restrict__ dst, float* __restrict__ elog,
    const unsigned* __restrict__ mx, float* __restrict__ den)
{
  int idx = blockIdx.x * 256 + threadIdx.x;
  if (idx >= NE * NH) return;
  int e = idx >> 3, h = idx & 7;
  int t = dst[e];
  unsigned u = mx[t * NH + h];
  float m = (u & 0x80000000u) ? __uint_as_float(u & 0x7FFFFFFFu)
                              : __uint_as_float(~u);
  float ex = expf(elog[idx] - m);
  elog[idx] = ex;
  atomicAdd(&den[t * NH + h], ex);
}

// ---------------------------------------------------------------------------
// Fused v = bond @ Wv, scaled by att[e,h], atomic scatter to ft[dst].
// Wv in 64KB LDS; each wave processes 4 edges at a time; lane covers cols
// l and l+64 (heads l>>4 and l>>4+4). Edge row loads use a wave-uniform
// base so they can be served by scalar loads.
// ---------------------------------------------------------------------------
__global__ __launch_bounds__(256) void v_scatter_k(
    const float* __restrict__ bond, const float* __restrict__ Wv,
    const int* __restrict__ dst, const float* __restrict__ elog,
    const float* __restrict__ den, float* __restrict__ ft)
{
  __shared__ float Wl[DIM * DIM];          // 64 KB
  for (int t = threadIdx.x; t < DIM * DIM; t += 256) Wl[t] = Wv[t];
  __syncthreads();
  const int wid = threadIdx.x >> 6;
  const int l   = threadIdx.x & 63;
  const int h0  = l >> 4, h1 = h0 + 4;
  for (int g = blockIdx.x * 4 + wid; g < NE / 4; g += gridDim.x * 4) {
    const int eu = __builtin_amdgcn_readfirstlane(g * 4);
    const float* __restrict__ rbase = bond + (size_t)eu * DIM;
    float acc[4][2] = {{0.f,0.f},{0.f,0.f},{0.f,0.f},{0.f,0.f}};
    #pragma unroll 8
    for (int i = 0; i < DIM; ++i) {
      float w0 = Wl[i * DIM + l];
      float w1 = Wl[i * DIM + l + 64];
      #pragma unroll
      for (int a = 0; a < 4; ++a) {
        float v = rbase[a * DIM + i];
        acc[a][0] = fmaf(v, w0, acc[a][0]);
        acc[a][1] = fmaf(v, w1, acc[a][1]);
      }
    }
    #pragma unroll
    for (int a = 0; a < 4; ++a) {
      int e = eu + a;
      int dn = dst[e];
      float at0 = elog[e * NH + h0] / (den[dn * NH + h0] + 1e-16f);
      float at1 = elog[e * NH + h1] / (den[dn * NH + h1] + 1e-16f);
      atomicAdd(&ft[(size_t)dn * DIM + l],      acc[a][0] * at0);
      atomicAdd(&ft[(size_t)dn * DIM + l + 64], acc[a][1] * at1);
    }
  }
}

// ---------------------------------------------------------------------------
// beta gate + LN1. One wave per node; lane holds elements 2l, 2l+1.
// ---------------------------------------------------------------------------
__global__ __launch_bounds__(256) void gate_ln_k(
    const float* __restrict__ ft, const float* __restrict__ x,
    const float* __restrict__ Wb, const float* __restrict__ g,
    const float* __restrict__ b, float* __restrict__ he,
    float* __restrict__ hout)
{
  const int wid = threadIdx.x >> 6;
  const int l   = threadIdx.x & 63;
  int n = blockIdx.x * 4 + wid;
  if (n >= NN) return;
  float2 f2 = *(const float2*)(ft + (size_t)n * DIM + 2 * l);
  float2 x2 = *(const float2*)(x  + (size_t)n * DIM + 2 * l);
  float s = f2.x * Wb[2*l]           + f2.y * Wb[2*l+1]
          + x2.x * Wb[DIM + 2*l]     + x2.y * Wb[DIM + 2*l+1]
          + (f2.x - x2.x) * Wb[2*DIM + 2*l]
          + (f2.y - x2.y) * Wb[2*DIM + 2*l+1];
  s = wave_sum64(s);
  float beta = 1.f / (1.f + expf(-s));
  float h0 = beta * x2.x + (1.f - beta) * f2.x;
  float h1 = beta * x2.y + (1.f - beta) * f2.y;
  *(float2*)(he + (size_t)n * DIM + 2 * l) = make_float2(h0, h1);
  float mu = wave_sum64(h0 + h1) * (1.f / DIM);
  float vr = wave_sum64(h0 * h0 + h1 * h1) * (1.f / DIM) - mu * mu;
  float rs = rsqrtf(vr + 1e-5f);
  float o0 = (h0 - mu) * rs * g[2*l]   + b[2*l];
  float o1 = (h1 - mu) * rs * g[2*l+1] + b[2*l+1];
  *(float2*)(hout + (size_t)n * DIM + 2 * l) = make_float2(o0, o1);
}

// ---------------------------------------------------------------------------
// FFN second half (k = 128..255) + partial + residual + final LN (g=1,b=0)
// ---------------------------------------------------------------------------
__global__ __launch_bounds__(256) void ffn2b_k(
    const float* __restrict__ hid, const float* __restrict__ W2,
    const float* __restrict__ part, const float* __restrict__ he,
    float* __restrict__ outp)
{
  __shared__ float Wl[DIM * DIM];          // rows 128..255 of W2
  for (int t = threadIdx.x; t < DIM * DIM; t += 256) Wl[t] = W2[DIM * DIM + t];
  __syncthreads();
  const int wid = threadIdx.x >> 6;
  const int l   = threadIdx.x & 63;
  for (int n = blockIdx.x * 4 + wid; n < NN; n += gridDim.x * 4) {
    const int nu = __builtin_amdgcn_readfirstlane(n);
    const float* __restrict__ row = hid + (size_t)nu * (2 * DIM) + DIM;
    float acc0 = 0.f, acc1 = 0.f;
    #pragma unroll 8
    for (int i = 0; i < DIM; ++i) {
      float v = row[i];
      acc0 = fmaf(v, Wl[i * DIM + l], acc0);
      acc1 = fmaf(v, Wl[i * DIM + l + 64], acc1);
    }
    float z0 = acc0 + part[(size_t)n * DIM + l]      + he[(size_t)n * DIM + l];
    float z1 = acc1 + part[(size_t)n * DIM + l + 64] + he[(size_t)n * DIM + l + 64];
    float mu = wave_sum64(z0 + z1) * (1.f / DIM);
    float vr = wave_sum64(z0 * z0 + z1 * z1) * (1.f / DIM) - mu * mu;
    float rs = rsqrtf(vr + 1e-5f);
    outp[(size_t)n * DIM + l]      = (z0 - mu) * rs;
    outp[(size_t)n * DIM + l + 64] = (z1 - mu) * rs;
  }
}

// ---------------------------------------------------------------------------
extern "C" void kernel_launch(void* const* d_in, const int* in_sizes, int n_in,
                              void* d_out, int out_size, void* d_ws, size_t ws_size,
                              hipStream_t stream)
{
  const float* node = (const float*)d_in[0];
  const float* bond = (const float*)d_in[1];
  const float* ba   = (const float*)d_in[2];
  const int*   src  = (const int*)  d_in[3];
  const int*   dst  = (const int*)  d_in[4];
  const float* Wk   = (const float*)d_in[5];
  const float* Wq   = (const float*)d_in[6];
  const float* Wv   = (const float*)d_in[7];
  const float* Wdis = (const float*)d_in[8];
  const float* Wb   = (const float*)d_in[9];
  const float* g1   = (const float*)d_in[10];
  const float* b1   = (const float*)d_in[11];
  const float* W1   = (const float*)d_in[12];
  const float* W2   = (const float*)d_in[13];
  float* out = (float*)d_out;

  // Workspace regions with disjoint lifetimes (total 32M floats = 128 MB):
  //  A (12.8M): q,k   (K1->K2)   | hid (FF1->FF2)
  //  B ( 6.4M): ft    (init->K5) | part (FF2a->FF2b)
  //  C ( 6.4M): elog  (K2->K4)   | he (K5->FF2b)   -- disjoint? elog dies at K4, he born K5. OK.
  //  D ( 6.4M): mx+den(K2->K4)   | hbuf (K5->FF1)
  float* ws   = (float*)d_ws;
  float* qb   = ws;                               // A
  float* kb   = qb + (size_t)NN * DIM;
  float* hid  = qb;                               // reuse A
  float* ftb  = ws + (size_t)12800000;            // B
  float* part = ftb;                              // reuse B
  float* elog = ws + (size_t)19200000;            // C (needs 5.12M)
  float* he   = elog;                             // reuse C
  unsigned* mx = (unsigned*)(ws + (size_t)25600000); // D
  float* den  = (float*)mx + (size_t)NN * NH;
  float* hbuf = (float*)(ws + (size_t)25600000);  // reuse D

  hipMemsetAsync(mx,  0, (size_t)NN * NH * 4, stream);
  hipMemsetAsync(den, 0, (size_t)NN * NH * 4, stream);
  hipMemsetAsync(ftb, 0, (size_t)NN * DIM * 4, stream);

  // q/k projections
  gemm128<<<512, 256, 0, stream>>>(node, DIM, Wq, DIM, 0, qb, DIM, 0, 0, NN);
  gemm128<<<512, 256, 0, stream>>>(node, DIM, Wk, DIM, 0, kb, DIM, 0, 0, NN);

  // edge softmax
  int egrid = (NE * NH + 255) / 256;
  edge_logits_k<<<egrid, 256, 0, stream>>>(kb, qb, ba, src, dst, Wdis, elog, mx);
  edge_exp_k<<<egrid, 256, 0, stream>>>(dst, elog, mx, den);

  // fused v-projection + attention scatter
  v_scatter_k<<<512, 256, 0, stream>>>(bond, Wv, dst, elog, den, ftb);

  // beta gate + LN1  (note: writes he into region C after elog is dead,
  // and hbuf into region D after mx/den are dead)
  gate_ln_k<<<(NN + 3) / 4, 256, 0, stream>>>(ftb, node, Wb, g1, b1, he, hbuf);

  // FFN: relu(h @ W1) @ W2, split into halves to fit 64KB LDS
  gemm128<<<512, 256, 0, stream>>>(hbuf, DIM, W1, 2 * DIM, 0,   hid, 2 * DIM, 0,   1, NN);
  gemm128<<<512, 256, 0, stream>>>(hbuf, DIM, W1, 2 * DIM, DIM, hid, 2 * DIM, DIM, 1, NN);
  gemm128<<<512, 256, 0, stream>>>(hid, 2 * DIM, W2, DIM, 0, part, DIM, 0, 0, NN);
  ffn2b_k<<<512, 256, 0, stream>>>(hid, W2, part, he, out);
}

// Round 2
// 1369.247 us; speedup vs baseline: 1.3200x; 1.3200x over previous
//
#include <hip/hip_runtime.h>
#include <math.h>

#define NN 50000
#define NE 640000
#define DIM 128
#define NH 8

__device__ __forceinline__ float wave_sum64(float v) {
  #pragma unroll
  for (int m = 32; m >= 1; m >>= 1) v += __shfl_xor(v, m, 64);
  return v;
}

// pack two f32 into bf16x2 (RNE), and unpack helpers
__device__ __forceinline__ unsigned bf16pk(float a, float b) {
  unsigned ua = __float_as_uint(a); ua = (ua + 0x7fffu + ((ua >> 16) & 1u)) >> 16;
  unsigned ub = __float_as_uint(b); ub = (ub + 0x7fffu + ((ub >> 16) & 1u)) & 0xffff0000u;
  return ua | ub;
}
__device__ __forceinline__ float bf_lo(unsigned v) { return __uint_as_float(v << 16); }
__device__ __forceinline__ float bf_hi(unsigned v) { return __uint_as_float(v & 0xffff0000u); }

// ---------------------------------------------------------------------------
// CSR build: deg count -> single-block scan -> fill
// ---------------------------------------------------------------------------
__global__ __launch_bounds__(256) void csr_count_k(const int* __restrict__ dst,
                                                   int* __restrict__ deg) {
  int e = blockIdx.x * 256 + threadIdx.x;
  if (e < NE) atomicAdd(&deg[dst[e]], 1);
}

#define SCAN_T 1024
#define SCHUNK 49   // ceil(50000/1024)
__global__ __launch_bounds__(1024) void scan_k(const int* __restrict__ deg,
                                               int* __restrict__ off,
                                               int* __restrict__ cursor) {
  __shared__ int part[SCAN_T];
  int t = threadIdx.x;
  int lo = t * SCHUNK, hi = lo + SCHUNK; if (hi > NN) hi = NN;
  int s = 0;
  for (int i = lo; i < hi; ++i) s += deg[i];
  part[t] = s;
  __syncthreads();
  for (int o = 1; o < SCAN_T; o <<= 1) {
    int v = (t >= o) ? part[t - o] : 0;
    __syncthreads();
    part[t] += v;
    __syncthreads();
  }
  int base = (t == 0) ? 0 : part[t - 1];
  for (int i = lo; i < hi; ++i) {
    off[i] = base; cursor[i] = base; base += deg[i];
  }
  if (t == SCAN_T - 1) off[NN] = part[SCAN_T - 1];
}

__global__ __launch_bounds__(256) void csr_fill_k(const int* __restrict__ dst,
                                                  int* __restrict__ cursor,
                                                  int* __restrict__ eids) {
  int e = blockIdx.x * 256 + threadIdx.x;
  if (e < NE) {
    int p = atomicAdd(&cursor[dst[e]], 1);
    eids[p] = e;
  }
}

// ---------------------------------------------------------------------------
// Fused q/k projection: qb = node@Wq, kb = node@Wk.
// Weights packed bf16 (cols c, c+64) in LDS. Shuffle-broadcast of x.
// Block 256 = 4 waves, 2 rows per wave.
// ---------------------------------------------------------------------------
__global__ __launch_bounds__(256) void qk_gemm_k(
    const float* __restrict__ node, const float* __restrict__ Wq,
    const float* __restrict__ Wk, float* __restrict__ qb,
    float* __restrict__ kb) {
  __shared__ unsigned Wqp[DIM * 64];  // 32 KB
  __shared__ unsigned Wkp[DIM * 64];  // 32 KB
  for (int t = threadIdx.x; t < DIM * 64; t += 256) {
    int i = t >> 6, c = t & 63;
    Wqp[t] = bf16pk(Wq[i * DIM + c], Wq[i * DIM + c + 64]);
    Wkp[t] = bf16pk(Wk[i * DIM + c], Wk[i * DIM + c + 64]);
  }
  __syncthreads();
  int wid = threadIdx.x >> 6, l = threadIdx.x & 63;
  for (int n0 = (blockIdx.x * 4 + wid) * 2; n0 < NN; n0 += gridDim.x * 8) {
    int n1 = n0 + 1;                       // NN even
    const float* r0 = node + (size_t)n0 * DIM;
    const float* r1 = node + (size_t)n1 * DIM;
    float x0a = r0[l], x0b = r0[l + 64], x1a = r1[l], x1b = r1[l + 64];
    float q00=0,q01=0,q10=0,q11=0,k00=0,k01=0,k10=0,k11=0;
    #pragma unroll 16
    for (int i = 0; i < 64; ++i) {
      unsigned wq = Wqp[i * 64 + l], wk = Wkp[i * 64 + l];
      float s0 = __shfl(x0a, i, 64), s1 = __shfl(x1a, i, 64);
      float ql = bf_lo(wq), qh = bf_hi(wq), kl = bf_lo(wk), kh = bf_hi(wk);
      q00 = fmaf(s0, ql, q00); q01 = fmaf(s0, qh, q01);
      q10 = fmaf(s1, ql, q10); q11 = fmaf(s1, qh, q11);
      k00 = fmaf(s0, kl, k00); k01 = fmaf(s0, kh, k01);
      k10 = fmaf(s1, kl, k10); k11 = fmaf(s1, kh, k11);
    }
    #pragma unroll 16
    for (int i = 0; i < 64; ++i) {
      unsigned wq = Wqp[(64 + i) * 64 + l], wk = Wkp[(64 + i) * 64 + l];
      float s0 = __shfl(x0b, i, 64), s1 = __shfl(x1b, i, 64);
      float ql = bf_lo(wq), qh = bf_hi(wq), kl = bf_lo(wk), kh = bf_hi(wk);
      q00 = fmaf(s0, ql, q00); q01 = fmaf(s0, qh, q01);
      q10 = fmaf(s1, ql, q10); q11 = fmaf(s1, qh, q11);
      k00 = fmaf(s0, kl, k00); k01 = fmaf(s0, kh, k01);
      k10 = fmaf(s1, kl, k10); k11 = fmaf(s1, kh, k11);
    }
    qb[(size_t)n0 * DIM + l] = q00; qb[(size_t)n0 * DIM + l + 64] = q01;
    qb[(size_t)n1 * DIM + l] = q10; qb[(size_t)n1 * DIM + l + 64] = q11;
    kb[(size_t)n0 * DIM + l] = k00; kb[(size_t)n0 * DIM + l + 64] = k01;
    kb[(size_t)n1 * DIM + l] = k10; kb[(size_t)n1 * DIM + l + 64] = k11;
  }
}

// ---------------------------------------------------------------------------
// Edge logits (no atomics): elog[e,h] = dot(k[src],q[dst])_h / 4 + ba*Wdis
// ---------------------------------------------------------------------------
__global__ __launch_bounds__(256) void edge_logits_k(
    const float* __restrict__ kbuf, const float* __restrict__ qbuf,
    const float* __restrict__ ba, const int* __restrict__ src,
    const int* __restrict__ dst, const float* __restrict__ Wdis,
    float* __restrict__ elog) {
  int idx = blockIdx.x * 256 + threadIdx.x;
  if (idx >= NE * NH) return;
  int e = idx >> 3, h = idx & 7;
  int s = src[e], t = dst[e];
  const float* kp = kbuf + (size_t)s * DIM + h * 16;
  const float* qp = qbuf + (size_t)t * DIM + h * 16;
  float sc = 0.f;
  #pragma unroll
  for (int i = 0; i < 16; ++i) sc = fmaf(kp[i], qp[i], sc);
  elog[idx] = sc * 0.25f + ba[e] * Wdis[h];
}

// ---------------------------------------------------------------------------
// Per-node fused kernel: softmax over in-edges (CSR), weighted bond gather
//   g[h,:] = sum_e att[e,h] * bond[e,:]     (per-head weighted sum)
//   ft[:]  = g[h(c),:] @ Wv[:,c]            (projection, Wv bf16 in LDS)
// then beta gate + LN1. One wave per node; block 256 = 4 nodes.
// LDS: 32K (Wv packed) + 16.6K (g) + 2.5K (params) ~= 51.8 KB -> 3 blk/CU.
// ---------------------------------------------------------------------------
__global__ __launch_bounds__(256) void node_attn_k(
    const float* __restrict__ bond, const float* __restrict__ WvG,
    const float* __restrict__ elog, const int* __restrict__ off,
    const int* __restrict__ eids, const float* __restrict__ x,
    const float* __restrict__ Wb, const float* __restrict__ g1,
    const float* __restrict__ b1, float* __restrict__ he,
    float* __restrict__ hbuf) {
  __shared__ unsigned Wvpk[DIM * 64];       // packed (c, c+64)
  __shared__ float gbuf[4][NH][130];        // per-wave g, padded
  __shared__ float WbL[3 * DIM];
  __shared__ float gl[DIM], bl[DIM];
  for (int t = threadIdx.x; t < DIM * 64; t += 256) {
    int i = t >> 6, c = t & 63;
    Wvpk[t] = bf16pk(WvG[i * DIM + c], WvG[i * DIM + c + 64]);
  }
  for (int t = threadIdx.x; t < 3 * DIM; t += 256) WbL[t] = Wb[t];
  for (int t = threadIdx.x; t < DIM; t += 256) { gl[t] = g1[t]; bl[t] = b1[t]; }
  __syncthreads();
  const int wid = threadIdx.x >> 6, l = threadIdx.x & 63;
  const int hh = l & 7, slot = l >> 3;
  for (int n = blockIdx.x * 4 + wid; n < NN; n += gridDim.x * 4) {
    int o0 = off[n];
    int deg = off[n + 1] - o0;
    float acc[16];
    #pragma unroll
    for (int i = 0; i < 16; ++i) acc[i] = 0.f;
    if (deg > 0) {
      // pass 1: per-head max (lane = (slot, head))
      float vmax = -1e30f;
      for (int j = slot; j < deg; j += 8) {
        int e = eids[o0 + j];
        vmax = fmaxf(vmax, elog[e * NH + hh]);
      }
      vmax = fmaxf(vmax, __shfl_xor(vmax, 8, 64));
      vmax = fmaxf(vmax, __shfl_xor(vmax, 16, 64));
      vmax = fmaxf(vmax, __shfl_xor(vmax, 32, 64));
      // pass 2: per-head denominator
      float den = 0.f;
      for (int j = slot; j < deg; j += 8) {
        int e = eids[o0 + j];
        den += __expf(elog[e * NH + hh] - vmax);
      }
      den += __shfl_xor(den, 8, 64);
      den += __shfl_xor(den, 16, 64);
      den += __shfl_xor(den, 32, 64);
      float rden = 1.f / (den + 1e-16f);
      // pass 3: weighted accumulation of bond rows (pipelined)
      int e = eids[o0];
      float2 b2 = *(const float2*)(bond + (size_t)e * DIM + 2 * l);
      float lg = elog[e * NH + hh];
      for (int j = 0; j < deg; ++j) {
        int en = e; float2 bn = b2; float lgn = lg;
        if (j + 1 < deg) {
          en = eids[o0 + j + 1];
          bn = *(const float2*)(bond + (size_t)en * DIM + 2 * l);
          lgn = elog[en * NH + hh];
        }
        float am = __expf(lg - vmax) * rden;   // att for head hh (8 replicas)
        #pragma unroll
        for (int h = 0; h < 8; ++h) {
          float ah = __shfl(am, h, 64);
          acc[2 * h]     = fmaf(ah, b2.x, acc[2 * h]);
          acc[2 * h + 1] = fmaf(ah, b2.y, acc[2 * h + 1]);
        }
        e = en; b2 = bn; lg = lgn;
      }
    }
    // stash g in wave-private LDS (no barrier needed)
    #pragma unroll
    for (int h = 0; h < 8; ++h) {
      gbuf[wid][h][2 * l]     = acc[2 * h];
      gbuf[wid][h][2 * l + 1] = acc[2 * h + 1];
    }
    // projection: ft cols (l, l+64); heads h0 = l>>4, h1 = 4 + (l>>4)
    int h0 = l >> 4, h1 = 4 + (l >> 4);
    float f0 = 0.f, f1 = 0.f;
    #pragma unroll 16
    for (int i = 0; i < DIM; ++i) {
      unsigned w = Wvpk[i * 64 + l];
      f0 = fmaf(gbuf[wid][h0][i], bf_lo(w), f0);
      f1 = fmaf(gbuf[wid][h1][i], bf_hi(w), f1);
    }
    // beta gate + LN1
    float x0 = x[(size_t)n * DIM + l], x1 = x[(size_t)n * DIM + l + 64];
    float s = f0 * WbL[l] + x0 * WbL[DIM + l] + (f0 - x0) * WbL[2 * DIM + l]
            + f1 * WbL[l + 64] + x1 * WbL[DIM + l + 64]
            + (f1 - x1) * WbL[2 * DIM + l + 64];
    s = wave_sum64(s);
    float beta = 1.f / (1.f + __expf(-s));
    float he0 = beta * x0 + (1.f - beta) * f0;
    float he1 = beta * x1 + (1.f - beta) * f1;
    he[(size_t)n * DIM + l] = he0;
    he[(size_t)n * DIM + l + 64] = he1;
    float mu = wave_sum64(he0 + he1) * (1.f / DIM);
    float vr = wave_sum64(he0 * he0 + he1 * he1) * (1.f / DIM) - mu * mu;
    float rs = rsqrtf(vr + 1e-5f);
    hbuf[(size_t)n * DIM + l]      = (he0 - mu) * rs * gl[l] + bl[l];
    hbuf[(size_t)n * DIM + l + 64] = (he1 - mu) * rs * gl[l + 64] + bl[l + 64];
  }
}

// ---------------------------------------------------------------------------
// FF1: hid = relu(hbuf @ W1), W1 [128][256] packed (c, c+128) in LDS (64 KB)
// ---------------------------------------------------------------------------
__global__ __launch_bounds__(256) void ff1_k(
    const float* __restrict__ xin, const float* __restrict__ W1,
    float* __restrict__ hid) {
  __shared__ unsigned Wp[DIM * DIM];  // 64 KB
  for (int t = threadIdx.x; t < DIM * DIM; t += 256) {
    int i = t >> 7, c = t & 127;
    Wp[t] = bf16pk(W1[i * 256 + c], W1[i * 256 + c + 128]);
  }
  __syncthreads();
  int wid = threadIdx.x >> 6, l = threadIdx.x & 63;
  for (int n0 = (blockIdx.x * 4 + wid) * 2; n0 < NN; n0 += gridDim.x * 8) {
    int n1 = n0 + 1;
    const float* r0 = xin + (size_t)n0 * DIM;
    const float* r1 = xin + (size_t)n1 * DIM;
    float x0a = r0[l], x0b = r0[l + 64], x1a = r1[l], x1b = r1[l + 64];
    float a[2][4] = {{0,0,0,0},{0,0,0,0}};
    #pragma unroll 16
    for (int i = 0; i < 64; ++i) {
      unsigned w0 = Wp[i * DIM + l], w1 = Wp[i * DIM + l + 64];
      float s0 = __shfl(x0a, i, 64), s1 = __shfl(x1a, i, 64);
      float c0 = bf_lo(w0), c2 = bf_hi(w0), c1 = bf_lo(w1), c3 = bf_hi(w1);
      a[0][0] = fmaf(s0, c0, a[0][0]); a[0][1] = fmaf(s0, c1, a[0][1]);
      a[0][2] = fmaf(s0, c2, a[0][2]); a[0][3] = fmaf(s0, c3, a[0][3]);
      a[1][0] = fmaf(s1, c0, a[1][0]); a[1][1] = fmaf(s1, c1, a[1][1]);
      a[1][2] = fmaf(s1, c2, a[1][2]); a[1][3] = fmaf(s1, c3, a[1][3]);
    }
    #pragma unroll 16
    for (int i = 0; i < 64; ++i) {
      unsigned w0 = Wp[(64 + i) * DIM + l], w1 = Wp[(64 + i) * DIM + l + 64];
      float s0 = __shfl(x0b, i, 64), s1 = __shfl(x1b, i, 64);
      float c0 = bf_lo(w0), c2 = bf_hi(w0), c1 = bf_lo(w1), c3 = bf_hi(w1);
      a[0][0] = fmaf(s0, c0, a[0][0]); a[0][1] = fmaf(s0, c1, a[0][1]);
      a[0][2] = fmaf(s0, c2, a[0][2]); a[0][3] = fmaf(s0, c3, a[0][3]);
      a[1][0] = fmaf(s1, c0, a[1][0]); a[1][1] = fmaf(s1, c1, a[1][1]);
      a[1][2] = fmaf(s1, c2, a[1][2]); a[1][3] = fmaf(s1, c3, a[1][3]);
    }
    float* o0 = hid + (size_t)n0 * 256;
    float* o1 = hid + (size_t)n1 * 256;
    o0[l]       = fmaxf(a[0][0], 0.f); o0[l + 64]  = fmaxf(a[0][1], 0.f);
    o0[l + 128] = fmaxf(a[0][2], 0.f); o0[l + 192] = fmaxf(a[0][3], 0.f);
    o1[l]       = fmaxf(a[1][0], 0.f); o1[l + 64]  = fmaxf(a[1][1], 0.f);
    o1[l + 128] = fmaxf(a[1][2], 0.f); o1[l + 192] = fmaxf(a[1][3], 0.f);
  }
}

// ---------------------------------------------------------------------------
// FF2 + residual + final LN (g=1,b=0). W2 [256][128] packed (c, c+64) (64 KB)
// ---------------------------------------------------------------------------
__global__ __launch_bounds__(256) void ff2_k(
    const float* __restrict__ hid, const float* __restrict__ W2,
    const float* __restrict__ he, float* __restrict__ outp) {
  __shared__ unsigned Wp[256 * 64];  // 64 KB
  for (int t = threadIdx.x; t < 256 * 64; t += 256) {
    int i = t >> 6, c = t & 63;
    Wp[t] = bf16pk(W2[i * DIM + c], W2[i * DIM + c + 64]);
  }
  __syncthreads();
  int wid = threadIdx.x >> 6, l = threadIdx.x & 63;
  for (int n0 = (blockIdx.x * 4 + wid) * 2; n0 < NN; n0 += gridDim.x * 8) {
    int n1 = n0 + 1;
    const float* r0 = hid + (size_t)n0 * 256;
    const float* r1 = hid + (size_t)n1 * 256;
    float x0[4] = {r0[l], r0[l + 64], r0[l + 128], r0[l + 192]};
    float x1[4] = {r1[l], r1[l + 64], r1[l + 128], r1[l + 192]};
    float a00 = 0, a01 = 0, a10 = 0, a11 = 0;
    #pragma unroll
    for (int q = 0; q < 4; ++q) {
      #pragma unroll 16
      for (int i = 0; i < 64; ++i) {
        unsigned w = Wp[(q * 64 + i) * 64 + l];
        float s0 = __shfl(x0[q], i, 64), s1 = __shfl(x1[q], i, 64);
        float cl = bf_lo(w), ch = bf_hi(w);
        a00 = fmaf(s0, cl, a00); a01 = fmaf(s0, ch, a01);
        a10 = fmaf(s1, cl, a10); a11 = fmaf(s1, ch, a11);
      }
    }
    float z00 = a00 + he[(size_t)n0 * DIM + l];
    float z01 = a01 + he[(size_t)n0 * DIM + l + 64];
    float z10 = a10 + he[(size_t)n1 * DIM + l];
    float z11 = a11 + he[(size_t)n1 * DIM + l + 64];
    float mu0 = wave_sum64(z00 + z01) * (1.f / DIM);
    float vr0 = wave_sum64(z00 * z00 + z01 * z01) * (1.f / DIM) - mu0 * mu0;
    float rs0 = rsqrtf(vr0 + 1e-5f);
    float mu1 = wave_sum64(z10 + z11) * (1.f / DIM);
    float vr1 = wave_sum64(z10 * z10 + z11 * z11) * (1.f / DIM) - mu1 * mu1;
    float rs1 = rsqrtf(vr1 + 1e-5f);
    outp[(size_t)n0 * DIM + l]      = (z00 - mu0) * rs0;
    outp[(size_t)n0 * DIM + l + 64] = (z01 - mu0) * rs0;
    outp[(size_t)n1 * DIM + l]      = (z10 - mu1) * rs1;
    outp[(size_t)n1 * DIM + l + 64] = (z11 - mu1) * rs1;
  }
}

// ---------------------------------------------------------------------------
extern "C" void kernel_launch(void* const* d_in, const int* in_sizes, int n_in,
                              void* d_out, int out_size, void* d_ws, size_t ws_size,
                              hipStream_t stream) {
  const float* node = (const float*)d_in[0];
  const float* bond = (const float*)d_in[1];
  const float* ba   = (const float*)d_in[2];
  const int*   src  = (const int*)  d_in[3];
  const int*   dst  = (const int*)  d_in[4];
  const float* Wk   = (const float*)d_in[5];
  const float* Wq   = (const float*)d_in[6];
  const float* Wv   = (const float*)d_in[7];
  const float* Wdis = (const float*)d_in[8];
  const float* Wb   = (const float*)d_in[9];
  const float* g1   = (const float*)d_in[10];
  const float* b1   = (const float*)d_in[11];
  const float* W1   = (const float*)d_in[12];
  const float* W2   = (const float*)d_in[13];
  float* out = (float*)d_out;

  // workspace layout (floats):
  //  [0,  6.4M)    qb      -> later he
  //  [6.4M,12.8M)  kb      -> later hbuf
  //  [12.8M,17.92M) elog
  //  [17.92M,30.72M) hid
  //  [30.72M, ...)  CSR ints: deg, off, cursor (NN+1 each), eids (NE)
  float* ws   = (float*)d_ws;
  float* qb   = ws;
  float* kb   = ws + (size_t)6400000;
  float* he   = qb;
  float* hbuf = kb;
  float* elog = ws + (size_t)12800000;
  float* hid  = ws + (size_t)17920000;
  int* deg    = (int*)(ws + (size_t)30720000);
  int* off    = deg + (NN + 1);
  int* cursor = off + (NN + 1);
  int* eids   = cursor + (NN + 1);

  hipMemsetAsync(deg, 0, (size_t)(NN + 1) * 4, stream);

  // CSR build
  csr_count_k<<<(NE + 255) / 256, 256, 0, stream>>>(dst, deg);
  scan_k<<<1, 1024, 0, stream>>>(deg, off, cursor);
  csr_fill_k<<<(NE + 255) / 256, 256, 0, stream>>>(dst, cursor, eids);

  // q/k projections (fused)
  qk_gemm_k<<<512, 256, 0, stream>>>(node, Wq, Wk, qb, kb);

  // edge logits (no atomics)
  edge_logits_k<<<(NE * NH + 255) / 256, 256, 0, stream>>>(
      kb, qb, ba, src, dst, Wdis, elog);

  // per-node: softmax + weighted bond gather + Wv projection + gate + LN1
  node_attn_k<<<768, 256, 0, stream>>>(bond, Wv, elog, off, eids, node,
                                       Wb, g1, b1, he, hbuf);

  // FFN
  ff1_k<<<512, 256, 0, stream>>>(hbuf, W1, hid);
  ff2_k<<<512, 256, 0, stream>>>(hid, W2, he, out);
}